// Round 1
// baseline (459.596 us; speedup 1.0000x reference)
//
#include <hip/hip_runtime.h>

// 12-bit ripple-borrow subtractor on binary spike inputs.
// Reference gate algebra is exact boolean logic on {0,1}, so per row:
//   pack bits (index 11 = LSB, index 0 = MSB), diff = (a - b) & 0xFFF,
//   final borrow = (b > a).
// Memory-bound: 621 MB total traffic -> ~100 us floor at 6.3 TB/s.

__global__ __launch_bounds__(256) void Subtractor12Bit_kernel(
    const float4* __restrict__ A4,   // [batch*3] float4 == [batch][12] float
    const float4* __restrict__ B4,
    float4* __restrict__ D4,         // diffs, [batch*3] float4
    float* __restrict__ Borrow,      // [batch]
    int batch)
{
    int row = blockIdx.x * blockDim.x + threadIdx.x;
    if (row >= batch) return;

    const int base = row * 3;
    float4 a0 = A4[base + 0];
    float4 a1 = A4[base + 1];
    float4 a2 = A4[base + 2];
    float4 b0 = B4[base + 0];
    float4 b1 = B4[base + 1];
    float4 b2 = B4[base + 2];

    // index 0 = MSB (bit 11) ... index 11 = LSB (bit 0)
    unsigned ua =
        ((unsigned)(a0.x > 0.5f) << 11) | ((unsigned)(a0.y > 0.5f) << 10) |
        ((unsigned)(a0.z > 0.5f) << 10 - 1) | ((unsigned)(a0.w > 0.5f) << 8) |
        ((unsigned)(a1.x > 0.5f) << 7)  | ((unsigned)(a1.y > 0.5f) << 6) |
        ((unsigned)(a1.z > 0.5f) << 5)  | ((unsigned)(a1.w > 0.5f) << 4) |
        ((unsigned)(a2.x > 0.5f) << 3)  | ((unsigned)(a2.y > 0.5f) << 2) |
        ((unsigned)(a2.z > 0.5f) << 1)  | ((unsigned)(a2.w > 0.5f));
    unsigned ub =
        ((unsigned)(b0.x > 0.5f) << 11) | ((unsigned)(b0.y > 0.5f) << 10) |
        ((unsigned)(b0.z > 0.5f) << 9)  | ((unsigned)(b0.w > 0.5f) << 8) |
        ((unsigned)(b1.x > 0.5f) << 7)  | ((unsigned)(b1.y > 0.5f) << 6) |
        ((unsigned)(b1.z > 0.5f) << 5)  | ((unsigned)(b1.w > 0.5f) << 4) |
        ((unsigned)(b2.x > 0.5f) << 3)  | ((unsigned)(b2.y > 0.5f) << 2) |
        ((unsigned)(b2.z > 0.5f) << 1)  | ((unsigned)(b2.w > 0.5f));

    unsigned diff = (ua - ub) & 0xFFFu;
    float borrow = (ub > ua) ? 1.0f : 0.0f;

    float4 d0, d1, d2;
    d0.x = (float)((diff >> 11) & 1u);
    d0.y = (float)((diff >> 10) & 1u);
    d0.z = (float)((diff >> 9) & 1u);
    d0.w = (float)((diff >> 8) & 1u);
    d1.x = (float)((diff >> 7) & 1u);
    d1.y = (float)((diff >> 6) & 1u);
    d1.z = (float)((diff >> 5) & 1u);
    d1.w = (float)((diff >> 4) & 1u);
    d2.x = (float)((diff >> 3) & 1u);
    d2.y = (float)((diff >> 2) & 1u);
    d2.z = (float)((diff >> 1) & 1u);
    d2.w = (float)(diff & 1u);

    D4[base + 0] = d0;
    D4[base + 1] = d1;
    D4[base + 2] = d2;
    Borrow[row] = borrow;
}

extern "C" void kernel_launch(void* const* d_in, const int* in_sizes, int n_in,
                              void* d_out, int out_size, void* d_ws, size_t ws_size,
                              hipStream_t stream) {
    const float* A = (const float*)d_in[0];
    const float* B = (const float*)d_in[1];
    float* out = (float*)d_out;

    const int batch = in_sizes[0] / 12;           // 4,194,304
    float* diffs = out;                           // [batch*12]
    float* borrow = out + (size_t)batch * 12;     // [batch]

    const int block = 256;
    const int grid = (batch + block - 1) / block;
    Subtractor12Bit_kernel<<<grid, block, 0, stream>>>(
        (const float4*)A, (const float4*)B, (float4*)diffs, borrow, batch);
}

// Round 2
// 457.728 us; speedup vs baseline: 1.0041x; 1.0041x over previous
//
#include <hip/hip_runtime.h>

// 12-bit ripple-borrow subtractor on binary spike inputs.
// Per row: pack 12 bits (idx 11 = LSB), diff = (a-b) & 0xFFF, borrow = (b>a).
//
// R2: fully-coalesced global access via LDS transpose staging.
//   - Global loads/stores: lane i touches consecutive float4 -> 1KB/instr/wave.
//   - LDS rows padded to 13 floats (13 coprime 32): every scalar LDS access
//     is <=2 lanes/bank == conflict-free on 32-bank/wave64 (m136).
//   - 26.6 KB LDS -> 6 blocks/CU -> 24 waves/CU.

#define ROWS 256          // rows per block == block size
#define LDS_STRIDE 13     // 12 + 1 pad

__global__ __launch_bounds__(256) void Subtractor12Bit_kernel(
    const float4* __restrict__ A4,   // [batch*3] float4
    const float4* __restrict__ B4,
    float4* __restrict__ D4,         // diffs as float4, [batch*3]
    float* __restrict__ Borrow,      // [batch]
    int batch)
{
    __shared__ float sa[ROWS * LDS_STRIDE];
    __shared__ float sb[ROWS * LDS_STRIDE];

    const int t = threadIdx.x;
    const int rowBase = blockIdx.x * ROWS;
    const int gbase = blockIdx.x * (ROWS * 3);      // float4 index base

    const bool full = (rowBase + ROWS) <= batch;

    // ---- Stage 1: coalesced global -> LDS ----
    #pragma unroll
    for (int k = 0; k < 3; ++k) {
        const int f = t + 256 * k;                  // local float4 idx 0..767
        const int r = f / 3;                        // local row
        const int c = (f % 3) * 4;                  // col 0/4/8
        const int addr = r * LDS_STRIDE + c;
        if (full || (rowBase + r) < batch) {
            const float4 a = A4[gbase + f];
            const float4 b = B4[gbase + f];
            sa[addr + 0] = a.x; sa[addr + 1] = a.y; sa[addr + 2] = a.z; sa[addr + 3] = a.w;
            sb[addr + 0] = b.x; sb[addr + 1] = b.y; sb[addr + 2] = b.z; sb[addr + 3] = b.w;
        }
    }
    __syncthreads();

    // ---- Stage 2: per-row compute (thread t owns local row t) ----
    const int row = rowBase + t;
    if (full || row < batch) {
        const int base = t * LDS_STRIDE;
        unsigned ua = 0u, ub = 0u;
        #pragma unroll
        for (int j = 0; j < 12; ++j) {
            ua |= (unsigned)(sa[base + j] > 0.5f) << (11 - j);
            ub |= (unsigned)(sb[base + j] > 0.5f) << (11 - j);
        }
        const unsigned diff = (ua - ub) & 0xFFFu;
        Borrow[row] = (ub > ua) ? 1.0f : 0.0f;      // coalesced 4B/lane
        // Write D bits back over sa (thread-private row region; no race).
        #pragma unroll
        for (int j = 0; j < 12; ++j)
            sa[base + j] = (float)((diff >> (11 - j)) & 1u);
    }
    __syncthreads();

    // ---- Stage 3: LDS -> coalesced global stores ----
    #pragma unroll
    for (int k = 0; k < 3; ++k) {
        const int f = t + 256 * k;
        const int r = f / 3;
        const int c = (f % 3) * 4;
        const int addr = r * LDS_STRIDE + c;
        if (full || (rowBase + r) < batch) {
            float4 d;
            d.x = sa[addr + 0]; d.y = sa[addr + 1]; d.z = sa[addr + 2]; d.w = sa[addr + 3];
            D4[gbase + f] = d;
        }
    }
}

extern "C" void kernel_launch(void* const* d_in, const int* in_sizes, int n_in,
                              void* d_out, int out_size, void* d_ws, size_t ws_size,
                              hipStream_t stream) {
    const float* A = (const float*)d_in[0];
    const float* B = (const float*)d_in[1];
    float* out = (float*)d_out;

    const int batch = in_sizes[0] / 12;             // 4,194,304
    float* diffs = out;                             // [batch*12]
    float* borrow = out + (size_t)batch * 12;       // [batch]

    const int grid = (batch + ROWS - 1) / ROWS;     // 16384
    Subtractor12Bit_kernel<<<grid, 256, 0, stream>>>(
        (const float4*)A, (const float4*)B, (float4*)diffs, borrow, batch);
}